// Round 3
// baseline (203.150 us; speedup 1.0000x reference)
//
#include <hip/hip_runtime.h>
#include <stdint.h>

#define B_   16384
#define D_   512
#define N1_  1024   // 2D
#define K1_  512    // D
#define N2_  512
#define K2_  1024

#define DELTA     4e-3f
#define LIST_CAP  (1u << 21)   // global borderline list: 2M entries, 8 MB
#define LCAP      2048u        // per-block LDS list (expected ~208 hits/block)

typedef _Float16 f16x8 __attribute__((ext_vector_type(8)));
typedef _Float16 f16x4 __attribute__((ext_vector_type(4)));
typedef float    f32x4 __attribute__((ext_vector_type(4)));
typedef uint32_t u32x4 __attribute__((ext_vector_type(4)));

// ---------------- prep: weights + biases + cvec ----------------
__global__ __launch_bounds__(256) void prep_w(
    const float* __restrict__ t,
    const float* __restrict__ W1, const float* __restrict__ b1,
    const float* __restrict__ W2, const float* __restrict__ b2,
    _Float16* __restrict__ w1h, _Float16* __restrict__ w2h,
    float* __restrict__ bias1, float* __restrict__ bias2,
    float* __restrict__ cvec, uint32_t* __restrict__ counter) {
  int blk = blockIdx.x, tid = threadIdx.x;
  if (blk < 2048) {                                 // W1 -> w1h (1024x512 f16, x64)
    int idx = blk * 256 + tid;
    int j = idx >> 9, k = idx & 511;
    w1h[idx] = (_Float16)(W1[(size_t)j * 513 + k] * 64.f);
  } else if (blk < 4096) {                          // W2 -> w2h (512x1024 f16)
    int idx = (blk - 2048) * 256 + tid;
    int i = idx >> 10, j = idx & 1023;
    w2h[idx] = (_Float16)W2[(size_t)i * 1025 + j];
  } else if (blk < 4100) {                          // biases + counter
    int j = (blk - 4096) * 256 + tid;
    float t0 = t[0];
    bias1[j] = b1[j] + t0 * W1[(size_t)j * 513 + 512];
    if (j < 512) bias2[j] = b2[j] + t0 * W2[(size_t)j * 1025 + 1024];
    if (j == 0) *counter = 0;
  } else {                                          // c[j] = sum_k W2[k,j]*W1[j,k]
    int wave = tid >> 6, lane = tid & 63;
    int j = (blk - 4100) * 4 + wave;
    float s = 0.f;
    #pragma unroll
    for (int kk = 0; kk < 8; ++kk) {
      int k = lane + kk * 64;
      s += W2[(size_t)k * 1025 + j] * W1[(size_t)j * 513 + k];
    }
    #pragma unroll
    for (int off = 32; off > 0; off >>= 1) s += __shfl_xor(s, off);
    if (lane == 0) cvec[j] = s;
  }
}

// ---------------- fused kernel, LDS-ring weight pipeline ----------------
// Block = 64 z-rows, 512 threads (8 waves, 2/SIMD), grid 256 (1 block/CU).
// 128 uniform slices of 16KB weights (W1: 4 chunks x 16 ks; W2: 4 chunks x 8 ks x 2
// col-halves) stream global->reg->LDS ring[3]. Issue(g+2) before compute(g),
// commit(g+1) after: data deps give counted vmcnt(2), loads span 2 barriers.
// Slice LDS layout: 128 rows(col-pairs) x 8 granules, g = (2q+e)^(r&7) -> conflict-free
// b128 reads + 64B-chunk coalesced staging loads.

#define ISSUE(g, R0, R1)                                                          \
  {                                                                               \
    int s_ = (g) & 31, ch_ = (g) >> 5;                                            \
    const char* a_;                                                               \
    size_t step_;                                                                 \
    if (s_ < 16) {                                                                \
      a_ = (const char*)w1h + (size_t)ch_ * 262144 + (size_t)s_ * 64 + w1o;       \
      step_ = 131072;                                                             \
    } else {                                                                      \
      int t_ = s_ - 16;                                                           \
      a_ = (const char*)w2h + (size_t)(t_ & 1) * 524288 + (size_t)ch_ * 512 +     \
           (size_t)(t_ >> 1) * 64 + w2o;                                          \
      step_ = 262144;                                                             \
    }                                                                             \
    R0 = *(const u32x4*)a_;                                                       \
    R1 = *(const u32x4*)(a_ + step_);                                             \
  }

#define COMMIT(g, R0, R1)                                                         \
  {                                                                               \
    char* sb_ = (char*)Wst[(g) % 3];                                              \
    *(u32x4*)(sb_ + tid * 16) = R0;                                               \
    *(u32x4*)(sb_ + 8192 + tid * 16) = R1;                                        \
  }

#define COMPUTE(g, HF2C)                                                          \
  {                                                                               \
    const char* sb_ = (const char*)Wst[(g) % 3];                                  \
    int s_ = (g) & 31;                                                            \
    f16x8 cw0_ = *(const f16x8*)(sb_ + cwo0);                                     \
    f16x8 cw1_ = *(const f16x8*)(sb_ + cwo1);                                     \
    if (s_ < 16) {                                                                \
      int zg_ = ((s_ * 4 + q) ^ sw) << 4;                                         \
      f16x8 zf_[4];                                                               \
      _Pragma("unroll")                                                           \
      for (int mt = 0; mt < 4; ++mt)                                              \
        zf_[mt] = *(const f16x8*)(azb + mt * 16384 + zg_);                        \
      __builtin_amdgcn_s_setprio(1);                                              \
      _Pragma("unroll")                                                           \
      for (int mt = 0; mt < 4; ++mt) {                                            \
        acc1[mt][0] = __builtin_amdgcn_mfma_f32_16x16x32_f16(cw0_, zf_[mt], acc1[mt][0], 0, 0, 0); \
        acc1[mt][1] = __builtin_amdgcn_mfma_f32_16x16x32_f16(cw1_, zf_[mt], acc1[mt][1], 0, 0, 0); \
      }                                                                           \
      __builtin_amdgcn_s_setprio(0);                                              \
    } else {                                                                      \
      if (HF2C == 0) {                                                            \
        int ks_ = (s_ - 16) >> 1;                                                 \
        int hg_ = ((ks_ * 4 + q) ^ sw) << 4;                                      \
        _Pragma("unroll")                                                         \
        for (int mt = 0; mt < 4; ++mt)                                            \
          hfP[mt] = *(const f16x8*)(hbb + mt * 8192 + hg_);                       \
      }                                                                           \
      __builtin_amdgcn_s_setprio(1);                                              \
      _Pragma("unroll")                                                           \
      for (int mt = 0; mt < 4; ++mt) {                                            \
        acc2[mt][HF2C * 2 + 0] = __builtin_amdgcn_mfma_f32_16x16x32_f16(cw0_, hfP[mt], acc2[mt][HF2C * 2 + 0], 0, 0, 0); \
        acc2[mt][HF2C * 2 + 1] = __builtin_amdgcn_mfma_f32_16x16x32_f16(cw1_, hfP[mt], acc2[mt][HF2C * 2 + 1], 0, 0, 0); \
      }                                                                           \
      __builtin_amdgcn_s_setprio(0);                                              \
    }                                                                             \
  }

#define CHUNK_EPI(g)                                                              \
  if (((g) & 31) == 15) {                                                         \
    int ch_ = (g) >> 5;                                                           \
    _Pragma("unroll")                                                             \
    for (int nt = 0; nt < 2; ++nt) {                                              \
      int colc = w * 32 + nt * 16 + q * 4;                                        \
      int col = ch_ * 256 + colc;                                                 \
      f32x4 b4 = *(const f32x4*)(bias1 + col);                                    \
      f32x4 c4 = *(const f32x4*)(cvec + col);                                     \
      _Pragma("unroll")                                                           \
      for (int mt = 0; mt < 4; ++mt) {                                            \
        int row = mt * 16 + m16;                                                  \
        f16x4 hv;                                                                 \
        _Pragma("unroll")                                                         \
        for (int r = 0; r < 4; ++r) {                                             \
          float hp = acc1[mt][nt][r] * (1.f / 1024.f) + b4[r];                    \
          hv[r] = (_Float16)(hp > 0.f ? hp : 0.f);                                \
          if (hp > 0.f) tr[mt] += c4[r];                                          \
          if (__builtin_fabsf(hp) < DELTA) {                                      \
            uint32_t i_ = atomicAdd(&lcnt, 1u);                                   \
            if (i_ < LCAP)                                                        \
              llist[i_] = ((uint32_t)(bm * 64 + row) << 10) | (uint32_t)(col + r) | \
                          (hp > 0.f ? 0x80000000u : 0u);                          \
          }                                                                       \
        }                                                                         \
        int gcol = colc >> 3;                                                     \
        *(f16x4*)((char*)Hb + row * 512 + ((gcol ^ (row & 7)) << 4) + (q & 1) * 8) = hv; \
        _Pragma("unroll")                                                         \
        for (int r = 0; r < 4; ++r) acc1[mt][nt][r] = 0.f;                        \
      }                                                                           \
    }                                                                             \
  }

__global__ __launch_bounds__(512) void fused_kernel(
    const float* __restrict__ z,
    const _Float16* __restrict__ w1h, const _Float16* __restrict__ w2h,
    const float* __restrict__ bias1, const float* __restrict__ bias2,
    const float* __restrict__ cvec,
    float* __restrict__ out, float* __restrict__ dlogp,
    uint32_t* __restrict__ list, uint32_t* __restrict__ counter) {
  __shared__ __align__(16) _Float16 Az[64 * 512];   // 64 KB swizzled z (f16 x16)
  __shared__ __align__(16) _Float16 Hb[64 * 256];   // 32 KB swizzled h chunk
  __shared__ __align__(16) char Wst[3][16384];      // 48 KB weight slice ring
  __shared__ uint32_t llist[LCAP];                  // 8 KB
  __shared__ float redbuf[8][64];                   // 2 KB
  __shared__ uint32_t lcnt, lbase;

  const int tid  = threadIdx.x;
  const int lane = tid & 63, w = tid >> 6;          // wave 0..7
  const int q    = lane >> 4, m16 = lane & 15;
  const int sw   = m16 & 7;
  const int bm   = blockIdx.x;

  if (tid == 0) lcnt = 0;

  // per-thread staging decode: granules u0=tid, u1=tid+512 of each slice.
  // u -> r=u>>3, g=u&7; v=g^(r&7); col=2r+(v&1); q=v>>1. u1: col+=128, same q.
  const int rr0 = tid >> 3;
  const int v0  = (tid & 7) ^ (rr0 & 7);
  const int cl0 = rr0 * 2 + (v0 & 1), qq0 = v0 >> 1;
  const size_t w1o = (size_t)cl0 * 1024 + (size_t)qq0 * 16;  // W1 col stride 1 KB
  const size_t w2o = (size_t)cl0 * 2048 + (size_t)qq0 * 16;  // W2 col stride 2 KB

  // consumer weight-fragment offsets within a slice (col c, k-quad q)
  int cwo0, cwo1;
  {
    int c0 = w * 32 + m16, r0 = c0 >> 1;
    cwo0 = r0 * 128 + (((q * 2 + (c0 & 1)) ^ (r0 & 7)) << 4);
    int c1 = w * 32 + 16 + m16, r1 = c1 >> 1;
    cwo1 = r1 * 128 + (((q * 2 + (c1 & 1)) ^ (r1 & 7)) << 4);
  }
  const char* azb = (const char*)Az + m16 * 1024;
  const char* hbb = (const char*)Hb + m16 * 512;

  // ---- stage z (f32 -> f16 x16) into swizzled Az ----
  {
    const float* zp = z + (size_t)bm * 64 * 512;
    #pragma unroll
    for (int i = 0; i < 16; ++i) {
      int slot = i * 512 + tid;
      int row = slot >> 7, u8 = slot & 127;
      f32x4 v = *(const f32x4*)(zp + (size_t)row * 512 + u8 * 4);
      f16x4 hv;
      #pragma unroll
      for (int r = 0; r < 4; ++r) hv[r] = (_Float16)(v[r] * 16.f);
      int gz = (u8 >> 1) ^ (row & 7);
      *(f16x4*)((char*)Az + row * 1024 + gz * 16 + (u8 & 1) * 8) = hv;
    }
  }

  f32x4 acc1[4][2] = {};
  f32x4 acc2[4][4] = {};
  f16x8 hfP[4] = {};
  float tr[4] = {0.f, 0.f, 0.f, 0.f};

  // ---- pipeline prologue ----
  u32x4 A0, A1, B0, B1;
  ISSUE(0, A0, A1);
  ISSUE(1, B0, B1);
  COMMIT(0, A0, A1);
  __syncthreads();

  // ---- 128-slice main pipeline (unroll-2 for static reg-set alternation) ----
  for (int g2 = 0; g2 < 128; g2 += 2) {
    if (g2 + 2 < 128) ISSUE(g2 + 2, A0, A1);
    COMPUTE(g2, 0);
    COMMIT(g2 + 1, B0, B1);
    __syncthreads();
    if (g2 + 3 < 128) ISSUE(g2 + 3, B0, B1);
    COMPUTE(g2 + 1, 1);
    if (g2 + 2 < 128) COMMIT(g2 + 2, A0, A1);
    CHUNK_EPI(g2 + 1);
    __syncthreads();
  }

  // ---- dz store: +bias2, coalesced f32x4 ----
  #pragma unroll
  for (int mt = 0; mt < 4; ++mt) {
    int row = bm * 64 + mt * 16 + m16;
    #pragma unroll
    for (int j = 0; j < 4; ++j) {
      int col = (j >> 1) * 256 + w * 32 + (j & 1) * 16 + q * 4;
      f32x4 b2v = *(const f32x4*)(bias2 + col);
      *(f32x4*)(out + (size_t)row * 512 + col) = acc2[mt][j] + b2v;
    }
  }

  // ---- trace: block-local, deterministic ----
  #pragma unroll
  for (int mt = 0; mt < 4; ++mt) {
    tr[mt] += __shfl_xor(tr[mt], 16);
    tr[mt] += __shfl_xor(tr[mt], 32);
  }
  if (q == 0) {
    #pragma unroll
    for (int mt = 0; mt < 4; ++mt) redbuf[w][mt * 16 + m16] = tr[mt];
  }
  __syncthreads();
  if (tid < 64) {
    float s = 0.f;
    #pragma unroll
    for (int ww = 0; ww < 8; ++ww) s += redbuf[ww][tid];
    dlogp[bm * 64 + tid] = -s;
  }

  // ---- flush borderline list: one device atomic per block ----
  if (tid == 0) {
    uint32_t n = lcnt < LCAP ? lcnt : LCAP;
    lbase = atomicAdd(counter, n);
  }
  __syncthreads();
  uint32_t n = lcnt < LCAP ? lcnt : LCAP;
  uint32_t base = lbase;
  for (uint32_t i = tid; i < n; i += 512) {
    uint32_t gi = base + i;
    if (gi < LIST_CAP) list[gi] = llist[i];
  }
}

// ---------------- fixup: recompute borderline h_pre in fp32, patch dlogp ----------------
__global__ __launch_bounds__(256)
void fixup_kernel(const float* __restrict__ z, const float* __restrict__ W1,
                  const float* __restrict__ bias1, const float* __restrict__ cvec,
                  const uint32_t* __restrict__ list, const uint32_t* __restrict__ counter,
                  float* __restrict__ dlogp) {
  uint32_t cnt = *counter;
  if (cnt > LIST_CAP) cnt = LIST_CAP;
  const int wid = (blockIdx.x * 256 + threadIdx.x) >> 6;
  const int lane = threadIdx.x & 63;
  const int nw = gridDim.x * 4;
  for (uint32_t i = wid; i < cnt; i += nw) {
    uint32_t e = list[i];
    int row = (int)((e >> 10) & 16383u);
    int col = (int)(e & 1023u);
    int oldm = (int)(e >> 31);
    float s = 0.f;
    #pragma unroll
    for (int it = 0; it < 8; ++it) {
      int k = it * 64 + lane;
      s += z[(size_t)row * 512 + k] * W1[(size_t)col * 513 + k];
    }
    #pragma unroll
    for (int off = 32; off > 0; off >>= 1) s += __shfl_xor(s, off);
    if (lane == 0) {
      float hp = s + bias1[col];
      int newm = hp > 0.f ? 1 : 0;
      if (newm != oldm)
        atomicAdd(&dlogp[row], oldm ? cvec[col] : -cvec[col]);
    }
  }
}

// ---------------- launcher ----------------
extern "C" void kernel_launch(void* const* d_in, const int* in_sizes, int n_in,
                              void* d_out, int out_size, void* d_ws, size_t ws_size,
                              hipStream_t stream) {
  const float* t  = (const float*)d_in[0];
  const float* z  = (const float*)d_in[1];
  // d_in[2] = logp_z, unused
  const float* W1 = (const float*)d_in[3];
  const float* b1 = (const float*)d_in[4];
  const float* W2 = (const float*)d_in[5];
  const float* b2 = (const float*)d_in[6];

  float* out   = (float*)d_out;
  float* dlogp = out + (size_t)B_ * D_;

  char* ws = (char*)d_ws;
  _Float16* w1h   = (_Float16*)ws; ws += (size_t)N1_ * K1_ * 2;  // 1 MB
  _Float16* w2h   = (_Float16*)ws; ws += (size_t)N2_ * K2_ * 2;  // 1 MB
  float*    bias1 = (float*)ws;    ws += 1024 * 4;
  float*    bias2 = (float*)ws;    ws += 512 * 4;
  float*    cvec  = (float*)ws;    ws += 1024 * 4;
  uint32_t* counter = (uint32_t*)ws; ws += 256;
  uint32_t* list  = (uint32_t*)ws; ws += (size_t)LIST_CAP * 4;   // 8 MB

  prep_w<<<4356, 256, 0, stream>>>(t, W1, b1, W2, b2, w1h, w2h, bias1, bias2, cvec, counter);
  fused_kernel<<<256, 512, 0, stream>>>(z, w1h, w2h, bias1, bias2, cvec, out, dlogp, list, counter);
  fixup_kernel<<<2048, 256, 0, stream>>>(z, W1, bias1, cvec, list, counter, dlogp);
}

// Round 4
// 198.534 us; speedup vs baseline: 1.0233x; 1.0233x over previous
//
#include <hip/hip_runtime.h>
#include <stdint.h>

#define B_   16384
#define D_   512
#define N1_  1024   // 2D
#define K1_  512    // D
#define N2_  512
#define K2_  1024

#define DELTA     4e-3f
#define LIST_CAP  (1u << 21)   // global borderline list: 2M entries, 8 MB
#define LCAP      1024u        // per-block LDS list (expected ~208 hits/block)

typedef _Float16 f16x8 __attribute__((ext_vector_type(8)));
typedef _Float16 f16x4 __attribute__((ext_vector_type(4)));
typedef float    f32x4 __attribute__((ext_vector_type(4)));

#define MFMA(a, b, c) __builtin_amdgcn_mfma_f32_16x16x32_f16(a, b, c, 0, 0, 0)

__device__ __forceinline__ void gl_lds16(const void* g, void* l) {
  __builtin_amdgcn_global_load_lds(
      (const __attribute__((address_space(1))) uint32_t*)g,
      (__attribute__((address_space(3))) uint32_t*)l, 16, 0, 0);
}

// ---------------- prep: permuted weights + biases + cvec ----------------
// wp: 128 slices x 16 KB, laid out in the EXACT byte order the fused kernel's
// LDS ring wants, so staging is linear global_load_lds (no reg roundtrip, no
// swizzle math in the hot loop). Slice g: ch=g>>5, s=g&31.
//   s<16 : W1 slice, cols ch*256+c, k = s*32+o*8  (x64 scale)
//   s>=16: t=s-16, hf=t&1, ks2=t>>1: W2 cols hf*256+c, k = ch*256+ks2*32+o*8
// byte u*16 within slice: r=u>>3, v=(u&7)^(r&7), c=2r+(v&1), o=v>>1.
__global__ __launch_bounds__(256) void prep_w(
    const float* __restrict__ t,
    const float* __restrict__ W1, const float* __restrict__ b1,
    const float* __restrict__ W2, const float* __restrict__ b2,
    _Float16* __restrict__ wp,
    float* __restrict__ bias1, float* __restrict__ bias2,
    float* __restrict__ cvec, uint32_t* __restrict__ counter) {
  int blk = blockIdx.x, tid = threadIdx.x;
  if (blk < 512) {                                  // permuted weight granules
    int idx = blk * 256 + tid;                      // [0, 131072)
    int g = idx >> 10, u = idx & 1023;
    int ch = g >> 5, s = g & 31;
    int r = u >> 3, v = (u & 7) ^ (r & 7);
    int c = 2 * r + (v & 1), o = v >> 1;
    const float* src;
    float scale;
    if (s < 16) {
      src = W1 + (size_t)(ch * 256 + c) * 513 + s * 32 + o * 8;
      scale = 64.f;
    } else {
      int tt = s - 16;
      src = W2 + (size_t)((tt & 1) * 256 + c) * 1025 + ch * 256 + (tt >> 1) * 32 + o * 8;
      scale = 1.f;
    }
    f16x8 hv;
    #pragma unroll
    for (int e = 0; e < 8; ++e) hv[e] = (_Float16)(src[e] * scale);
    *(f16x8*)(wp + (size_t)idx * 8) = hv;
  } else if (blk < 516) {                           // biases + counter
    int j = (blk - 512) * 256 + tid;                // [0, 1024)
    float t0 = t[0];
    bias1[j] = b1[j] + t0 * W1[(size_t)j * 513 + 512];
    if (j < 512) bias2[j] = b2[j] + t0 * W2[(size_t)j * 1025 + 1024];
    if (j == 0) *counter = 0;
  } else {                                          // c[j] = sum_k W2[k,j]*W1[j,k]
    int wave = tid >> 6, lane = tid & 63;
    int j = (blk - 516) * 4 + wave;                 // [0, 1024)
    float s = 0.f;
    #pragma unroll
    for (int kk = 0; kk < 8; ++kk) {
      int k = lane + kk * 64;
      s += W2[(size_t)k * 1025 + j] * W1[(size_t)j * 513 + k];
    }
    #pragma unroll
    for (int off = 32; off > 0; off >>= 1) s += __shfl_xor(s, off);
    if (lane == 0) cvec[j] = s;
  }
}

// ---------------- fused kernel: wave-private weight pipelines ----------------
// Block = 64 z-rows, 512 threads, grid 256 (1 block/CU). Wave w consumes exactly
// bytes [w*2048, +2048) of each 16KB slice, and stages exactly those bytes via
// 2x global_load_lds16 (linear dest = uniform base + lane*16). The 3-slot ring
// is therefore WAVE-PRIVATE: no barriers for slice readiness, just a per-wave
// counted s_waitcnt vmcnt(2) (slice g+1's 2 loads stay in flight). Waves
// free-run; __syncthreads only for Az (once) and Hb chunk handoff (2/chunk).

#define ISSUE_G(gi)                                                            \
  {                                                                            \
    int gi_ = (gi);                                                            \
    int ga_ = gi_ > 127 ? 127 : gi_;                                           \
    int is_ = gi_ % 3;                                                         \
    const char* sp_ = (const char*)wp + (size_t)ga_ * 16384 + woff;            \
    char* dp_ = (char*)ring + is_ * 16384 + woff;                              \
    gl_lds16(sp_, dp_);                                                        \
    gl_lds16(sp_ + 1024, dp_ + 1024);                                          \
  }

__global__ __launch_bounds__(512) void fused_kernel(
    const float* __restrict__ z, const _Float16* __restrict__ wp,
    const float* __restrict__ bias1, const float* __restrict__ bias2,
    const float* __restrict__ cvec,
    float* __restrict__ out, float* __restrict__ dlogp,
    uint32_t* __restrict__ list, uint32_t* __restrict__ counter) {
  __shared__ __align__(16) _Float16 Az[64 * 512];   // 64 KB swizzled z (f16 x16)
  __shared__ __align__(16) _Float16 Hb[64 * 256];   // 32 KB swizzled h chunk
  __shared__ __align__(16) char ring[3][16384];     // 48 KB wave-private slice ring
  __shared__ float bias1L[1024], cvecL[1024];       // 8 KB
  __shared__ uint32_t llist[LCAP];                  // 4 KB
  __shared__ float redbuf[8][64];                   // 2 KB
  __shared__ uint32_t lcnt, lbase;                  // total 161800 B

  const int tid  = threadIdx.x;
  const int lane = tid & 63, w = tid >> 6;          // wave 0..7
  const int q    = lane >> 4, m16 = lane & 15;
  const int sw   = m16 & 7;
  const int bm   = blockIdx.x;

  // staging offset: wave-private region [w*2048, +2048) of each slice
  const int woff = tid * 16 + (tid >> 6) * 1024;

  // consumer weight-fragment offsets within a slice (cols w*32+m16, +16)
  int cwo0, cwo1;
  {
    int c0 = w * 32 + m16, r0 = c0 >> 1;
    cwo0 = r0 * 128 + (((q * 2 + (c0 & 1)) ^ (r0 & 7)) << 4);
    int c1 = c0 + 16, r1 = c1 >> 1;
    cwo1 = r1 * 128 + (((q * 2 + (c1 & 1)) ^ (r1 & 7)) << 4);
  }
  const char* azb = (const char*)Az + m16 * 1024;
  const char* hbb = (const char*)Hb + m16 * 512;
  char*       hbw = (char*)Hb;

  if (tid == 0) lcnt = 0;

  // ---- stage z (f32 -> f16 x16) into swizzled Az ----
  {
    const float* zp = z + (size_t)bm * 64 * 512;
    #pragma unroll
    for (int i = 0; i < 16; ++i) {
      int slot = i * 512 + tid;
      int row = slot >> 7, u8 = slot & 127;
      f32x4 v = *(const f32x4*)(zp + (size_t)row * 512 + u8 * 4);
      f16x4 hv;
      #pragma unroll
      for (int r = 0; r < 4; ++r) hv[r] = (_Float16)(v[r] * 16.f);
      int gz = (u8 >> 1) ^ (row & 7);
      *(f16x4*)((char*)Az + row * 1024 + gz * 16 + (u8 & 1) * 8) = hv;
    }
  }
  // ---- stage bias1/cvec into LDS (keeps the K-loop free of stray VMEM ops) ----
  for (int i = tid; i < 1024; i += 512) {
    bias1L[i] = bias1[i];
    cvecL[i]  = cvec[i];
  }
  __syncthreads();   // Az + biases ready; vmcnt drained to 0 for all waves

  f32x4 acc1[4][2] = {};
  f32x4 acc2[4][4] = {};
  f16x8 hfP[4] = {};
  float tr[4] = {0.f, 0.f, 0.f, 0.f};

  // ---- pipeline prologue: slices 0,1 in flight (4 vmem ops/wave) ----
  ISSUE_G(0);
  ISSUE_G(1);

  for (int ch = 0; ch < 4; ++ch) {
    const int ch32 = ch * 32;
    const int c3 = ch32 % 3;

    // ---- 16 W1 phases: h_pre chunk ch (no barriers, wave-private ring) ----
    #pragma unroll
    for (int s = 0; s < 16; ++s) {
      const int zg = ((s * 4 + q) ^ sw) << 4;
      f16x8 zf0 = *(const f16x8*)(azb + 0 * 16384 + zg);
      f16x8 zf1 = *(const f16x8*)(azb + 1 * 16384 + zg);
      f16x8 zf2 = *(const f16x8*)(azb + 2 * 16384 + zg);
      f16x8 zf3 = *(const f16x8*)(azb + 3 * 16384 + zg);
      asm volatile("s_waitcnt vmcnt(2)" ::: "memory");
      int sl = c3 + (s % 3); if (sl >= 3) sl -= 3;
      const char* rb = (const char*)ring + sl * 16384;
      f16x8 cw0 = *(const f16x8*)(rb + cwo0);
      f16x8 cw1 = *(const f16x8*)(rb + cwo1);
      __builtin_amdgcn_s_setprio(1);
      acc1[0][0] = MFMA(cw0, zf0, acc1[0][0]);
      acc1[0][1] = MFMA(cw1, zf0, acc1[0][1]);
      acc1[1][0] = MFMA(cw0, zf1, acc1[1][0]);
      acc1[1][1] = MFMA(cw1, zf1, acc1[1][1]);
      acc1[2][0] = MFMA(cw0, zf2, acc1[2][0]);
      acc1[2][1] = MFMA(cw1, zf2, acc1[2][1]);
      acc1[3][0] = MFMA(cw0, zf3, acc1[3][0]);
      acc1[3][1] = MFMA(cw1, zf3, acc1[3][1]);
      __builtin_amdgcn_s_setprio(0);
      ISSUE_G(ch32 + s + 2);
    }

    __syncthreads();   // all waves done with Hb(ch-1) reads (drains pipeline briefly)

    // ---- chunk epilogue: bias+relu, trace, borderline list, h chunk -> Hb ----
    #pragma unroll
    for (int nt = 0; nt < 2; ++nt) {
      int colc = w * 32 + nt * 16 + q * 4;
      int col = ch * 256 + colc;
      f32x4 b4 = *(const f32x4*)&bias1L[col];
      f32x4 c4 = *(const f32x4*)&cvecL[col];
      #pragma unroll
      for (int mt = 0; mt < 4; ++mt) {
        int row = mt * 16 + m16;
        f16x4 hv;
        #pragma unroll
        for (int r = 0; r < 4; ++r) {
          float hp = acc1[mt][nt][r] * (1.f / 1024.f) + b4[r];
          hv[r] = (_Float16)(hp > 0.f ? hp : 0.f);
          if (hp > 0.f) tr[mt] += c4[r];
          if (__builtin_fabsf(hp) < DELTA) {
            uint32_t i_ = atomicAdd(&lcnt, 1u);
            if (i_ < LCAP)
              llist[i_] = ((uint32_t)(bm * 64 + row) << 10) | (uint32_t)(col + r) |
                          (hp > 0.f ? 0x80000000u : 0u);
          }
        }
        int gcol = colc >> 3;
        *(f16x4*)(hbw + row * 512 + ((gcol ^ (row & 7)) << 4) + (q & 1) * 8) = hv;
        #pragma unroll
        for (int r = 0; r < 4; ++r) acc1[mt][nt][r] = 0.f;
      }
    }
    __syncthreads();   // Hb(ch) visible to all waves

    // ---- 16 W2 phases: dz += h_chunk @ W2[:,chunk]^T (hf = t&1, ks2 = t>>1) ----
    #pragma unroll
    for (int t = 0; t < 16; ++t) {
      if ((t & 1) == 0) {
        const int hg = (((t >> 1) * 4 + q) ^ sw) << 4;
        hfP[0] = *(const f16x8*)(hbb + 0 * 8192 + hg);
        hfP[1] = *(const f16x8*)(hbb + 1 * 8192 + hg);
        hfP[2] = *(const f16x8*)(hbb + 2 * 8192 + hg);
        hfP[3] = *(const f16x8*)(hbb + 3 * 8192 + hg);
      }
      asm volatile("s_waitcnt vmcnt(2)" ::: "memory");
      int sl = c3 + ((16 + t) % 3); if (sl >= 3) sl -= 3;
      const char* rb = (const char*)ring + sl * 16384;
      f16x8 cw0 = *(const f16x8*)(rb + cwo0);
      f16x8 cw1 = *(const f16x8*)(rb + cwo1);
      const int j0 = (t & 1) * 2;
      __builtin_amdgcn_s_setprio(1);
      acc2[0][j0 + 0] = MFMA(cw0, hfP[0], acc2[0][j0 + 0]);
      acc2[0][j0 + 1] = MFMA(cw1, hfP[0], acc2[0][j0 + 1]);
      acc2[1][j0 + 0] = MFMA(cw0, hfP[1], acc2[1][j0 + 0]);
      acc2[1][j0 + 1] = MFMA(cw1, hfP[1], acc2[1][j0 + 1]);
      acc2[2][j0 + 0] = MFMA(cw0, hfP[2], acc2[2][j0 + 0]);
      acc2[2][j0 + 1] = MFMA(cw1, hfP[2], acc2[2][j0 + 1]);
      acc2[3][j0 + 0] = MFMA(cw0, hfP[3], acc2[3][j0 + 0]);
      acc2[3][j0 + 1] = MFMA(cw1, hfP[3], acc2[3][j0 + 1]);
      __builtin_amdgcn_s_setprio(0);
      ISSUE_G(ch32 + 16 + t + 2);
    }
  }

  __syncthreads();   // drain dangling dummy prefetches; all LDS traffic done

  // ---- dz store: +bias2, coalesced f32x4 (4 consecutive cols per thread) ----
  #pragma unroll
  for (int mt = 0; mt < 4; ++mt) {
    int row = bm * 64 + mt * 16 + m16;
    #pragma unroll
    for (int j = 0; j < 4; ++j) {
      int col = (j >> 1) * 256 + w * 32 + (j & 1) * 16 + q * 4;
      f32x4 b2v = *(const f32x4*)(bias2 + col);
      *(f32x4*)(out + (size_t)row * 512 + col) = acc2[mt][j] + b2v;
    }
  }

  // ---- trace: block-local, deterministic ----
  #pragma unroll
  for (int mt = 0; mt < 4; ++mt) {
    tr[mt] += __shfl_xor(tr[mt], 16);
    tr[mt] += __shfl_xor(tr[mt], 32);
  }
  if (q == 0) {
    #pragma unroll
    for (int mt = 0; mt < 4; ++mt) redbuf[w][mt * 16 + m16] = tr[mt];
  }
  __syncthreads();
  if (tid < 64) {
    float s = 0.f;
    #pragma unroll
    for (int ww = 0; ww < 8; ++ww) s += redbuf[ww][tid];
    dlogp[bm * 64 + tid] = -s;
  }

  // ---- flush borderline list: one device atomic per block ----
  if (tid == 0) {
    uint32_t n = lcnt < LCAP ? lcnt : LCAP;
    lbase = atomicAdd(counter, n);
  }
  __syncthreads();
  uint32_t n = lcnt < LCAP ? lcnt : LCAP;
  uint32_t base = lbase;
  for (uint32_t i = tid; i < n; i += 512) {
    uint32_t gi = base + i;
    if (gi < LIST_CAP) list[gi] = llist[i];
  }
}

// ---------------- fixup: recompute borderline h_pre in fp32, patch dlogp ----------------
__global__ __launch_bounds__(256)
void fixup_kernel(const float* __restrict__ z, const float* __restrict__ W1,
                  const float* __restrict__ bias1, const float* __restrict__ cvec,
                  const uint32_t* __restrict__ list, const uint32_t* __restrict__ counter,
                  float* __restrict__ dlogp) {
  uint32_t cnt = *counter;
  if (cnt > LIST_CAP) cnt = LIST_CAP;
  const int wid = (blockIdx.x * 256 + threadIdx.x) >> 6;
  const int lane = threadIdx.x & 63;
  const int nw = gridDim.x * 4;
  for (uint32_t i = wid; i < cnt; i += nw) {
    uint32_t e = list[i];
    int row = (int)((e >> 10) & 16383u);
    int col = (int)(e & 1023u);
    int oldm = (int)(e >> 31);
    float s = 0.f;
    #pragma unroll
    for (int it = 0; it < 8; ++it) {
      int k = it * 64 + lane;
      s += z[(size_t)row * 512 + k] * W1[(size_t)col * 513 + k];
    }
    #pragma unroll
    for (int off = 32; off > 0; off >>= 1) s += __shfl_xor(s, off);
    if (lane == 0) {
      float hp = s + bias1[col];
      int newm = hp > 0.f ? 1 : 0;
      if (newm != oldm)
        atomicAdd(&dlogp[row], oldm ? cvec[col] : -cvec[col]);
    }
  }
}

// ---------------- launcher ----------------
extern "C" void kernel_launch(void* const* d_in, const int* in_sizes, int n_in,
                              void* d_out, int out_size, void* d_ws, size_t ws_size,
                              hipStream_t stream) {
  const float* t  = (const float*)d_in[0];
  const float* z  = (const float*)d_in[1];
  // d_in[2] = logp_z, unused
  const float* W1 = (const float*)d_in[3];
  const float* b1 = (const float*)d_in[4];
  const float* W2 = (const float*)d_in[5];
  const float* b2 = (const float*)d_in[6];

  float* out   = (float*)d_out;
  float* dlogp = out + (size_t)B_ * D_;

  char* ws = (char*)d_ws;
  _Float16* wp    = (_Float16*)ws; ws += (size_t)128 * 16384;    // 2 MB permuted weights
  float*    bias1 = (float*)ws;    ws += 1024 * 4;
  float*    bias2 = (float*)ws;    ws += 512 * 4;
  float*    cvec  = (float*)ws;    ws += 1024 * 4;
  uint32_t* counter = (uint32_t*)ws; ws += 256;
  uint32_t* list  = (uint32_t*)ws; ws += (size_t)LIST_CAP * 4;   // 8 MB

  prep_w<<<772, 256, 0, stream>>>(t, W1, b1, W2, b2, wp, bias1, bias2, cvec, counter);
  fused_kernel<<<256, 512, 0, stream>>>(z, wp, bias1, bias2, cvec, out, dlogp, list, counter);
  fixup_kernel<<<2048, 256, 0, stream>>>(z, W1, bias1, cvec, list, counter, dlogp);
}

// Round 5
// 159.476 us; speedup vs baseline: 1.2739x; 1.2449x over previous
//
#include <hip/hip_runtime.h>
#include <stdint.h>

#define B_   16384
#define D_   512
#define N1_  1024   // 2D
#define K1_  512    // D
#define N2_  512
#define K2_  1024

#define DELTA     4e-3f
#define LIST_CAP  (1u << 21)   // global borderline list: 2M entries, 8 MB
#define LCAP      1024u        // per-block LDS list (expected ~209 hits/block)

typedef _Float16 f16x8 __attribute__((ext_vector_type(8)));
typedef _Float16 f16x4 __attribute__((ext_vector_type(4)));
typedef float    f32x4 __attribute__((ext_vector_type(4)));

#define MFMA(a, b, c) __builtin_amdgcn_mfma_f32_16x16x32_f16(a, b, c, 0, 0, 0)

// ---------------- prep: frag-major permuted weights + biases + cvec ----------------
// wp: 64 slices x 32 KB. Slice g (ch=g>>5, ph=g&31) holds the k32-slice of the
// chunk-ch GEMM (ph<16: W1 cols ch*512.., k=ph*32; ph>=16: W2 all 512 dz-cols,
// k=ch*512+(ph-16)*32). Within a slice: [wave w: 4KB][nt 0..3: 1KB][lane: 16B]
// = exactly the A-operand fragment each lane consumes -> 16B/lane coalesced
// global loads, no LDS for weights at all (each weight byte is read by ONE wave).
__global__ __launch_bounds__(256) void prep_w(
    const float* __restrict__ t,
    const float* __restrict__ W1, const float* __restrict__ b1,
    const float* __restrict__ W2, const float* __restrict__ b2,
    _Float16* __restrict__ wp,
    float* __restrict__ bias1, float* __restrict__ bias2,
    float* __restrict__ cvec, uint32_t* __restrict__ counter) {
  int blk = blockIdx.x, tid = threadIdx.x;
  if (blk < 512) {                                  // 131072 granules of 16 B
    int idx = blk * 256 + tid;
    int g = idx >> 11, rem = idx & 2047;
    int w = rem >> 8, nt = (rem >> 6) & 3, lane = rem & 63;
    int m16 = lane & 15, q = lane >> 4;
    int ch = g >> 5, ph = g & 31;
    const float* src;
    float scale;
    if (ph < 16) {                                  // W1 frag: m=h-col, k
      int col = ch * 512 + w * 64 + nt * 16 + m16;
      int k = ph * 32 + q * 8;
      src = W1 + (size_t)col * 513 + k;
      scale = 64.f;
    } else {                                        // W2 frag: m=dz-col, k=h-col
      int col = w * 64 + nt * 16 + m16;
      int k = ch * 512 + (ph - 16) * 32 + q * 8;
      src = W2 + (size_t)col * 1025 + k;
      scale = 1.f;
    }
    f16x8 hv;
    #pragma unroll
    for (int e = 0; e < 8; ++e) hv[e] = (_Float16)(src[e] * scale);
    *(f16x8*)(wp + (size_t)idx * 8) = hv;
  } else if (blk < 516) {                           // biases + counter
    int j = (blk - 512) * 256 + tid;                // [0, 1024)
    float t0 = t[0];
    bias1[j] = b1[j] + t0 * W1[(size_t)j * 513 + 512];
    if (j < 512) bias2[j] = b2[j] + t0 * W2[(size_t)j * 1025 + 1024];
    if (j == 0) *counter = 0;
  } else {                                          // c[j] = sum_k W2[k,j]*W1[j,k]
    int wave = tid >> 6, lane = tid & 63;
    int j = (blk - 516) * 4 + wave;                 // [0, 1024)
    float s = 0.f;
    #pragma unroll
    for (int kk = 0; kk < 8; ++kk) {
      int k = lane + kk * 64;
      s += W2[(size_t)k * 1025 + j] * W1[(size_t)j * 513 + k];
    }
    #pragma unroll
    for (int off = 32; off > 0; off >>= 1) s += __shfl_xor(s, off);
    if (lane == 0) cvec[j] = s;
  }
}

// ---------------- fused: weights global->reg, z/h in LDS, 64x64 wave tiles ----------------
// Block = 64 z-rows, 512 threads (8 waves), grid 256 (1 block/CU).
// Wave w owns cols [w*64,+64) of each 512-col chunk (GEMM1) and of dz (GEMM2).
// Weights: one continuous 64-slice register-double-buffered prefetch stream
// (cwA/cwB), plain C loads -> compiler-managed waits. LDS holds only Az (64KB,
// XOR-swizzled z) and Hb (64KB, XOR-swizzled h chunk). 4 barriers total.

__global__ __launch_bounds__(512) void fused_kernel(
    const float* __restrict__ z, const _Float16* __restrict__ wp,
    const float* __restrict__ bias1, const float* __restrict__ bias2,
    const float* __restrict__ cvec,
    float* __restrict__ out, float* __restrict__ dlogp,
    uint32_t* __restrict__ list, uint32_t* __restrict__ counter) {
  __shared__ __align__(16) _Float16 Az[64 * 512];   // 64 KB swizzled z (f16 x16)
  __shared__ __align__(16) _Float16 Hb[64 * 512];   // 64 KB swizzled h chunk
  __shared__ __align__(16) float bias1L[1024];      // 4 KB
  __shared__ __align__(16) float cvecL[1024];       // 4 KB
  __shared__ uint32_t llist[LCAP];                  // 4 KB
  __shared__ float redbuf[8][64];                   // 2 KB
  __shared__ uint32_t lcnt, lbase;                  // ~142 KB total

  const int tid  = threadIdx.x;
  const int lane = tid & 63, w = tid >> 6;          // wave 0..7
  const int q    = lane >> 4, m16 = lane & 15;
  const int sw   = m16 & 7;
  const int bm   = blockIdx.x;

  if (tid == 0) lcnt = 0;

  // ---- stage z (f32 -> f16 x16) into swizzled Az ----
  {
    const float* zp = z + (size_t)bm * 64 * 512;
    #pragma unroll
    for (int i = 0; i < 16; ++i) {
      int slot = i * 512 + tid;
      int row = slot >> 7, u8 = slot & 127;
      f32x4 v = *(const f32x4*)(zp + (size_t)row * 512 + u8 * 4);
      f16x4 hv;
      #pragma unroll
      for (int r = 0; r < 4; ++r) hv[r] = (_Float16)(v[r] * 16.f);
      int gz = (u8 >> 1) ^ (row & 7);
      *(f16x4*)((char*)Az + row * 1024 + gz * 16 + (u8 & 1) * 8) = hv;
    }
  }
  for (int i = tid; i < 1024; i += 512) {
    bias1L[i] = bias1[i];
    cvecL[i]  = cvec[i];
  }
  __syncthreads();

  f32x4 acc1[4][4] = {};                            // GEMM1: [mt(row)][nt(col)]
  f32x4 acc2[4][4] = {};                            // GEMM2 accumulates across chunks
  float tr[4] = {0.f, 0.f, 0.f, 0.f};

  const char* azb   = (const char*)Az + m16 * 1024;
  const char* hbb   = (const char*)Hb + m16 * 1024;
  const char* wbase = (const char*)wp + w * 4096 + lane * 16;

  // weight prefetch stream: slice g fragments at wbase + g*32768 + nt*1024
  f16x8 cwA[4], cwB[4];
  #pragma unroll
  for (int nt = 0; nt < 4; ++nt) cwA[nt] = *(const f16x8*)(wbase + nt * 1024);

  for (int ch = 0; ch < 2; ++ch) {
    // ---- GEMM1: 16 k32-slices, h_pre chunk (cols ch*512..+512) ----
    for (int s2 = 0; s2 < 8; ++s2) {
      const int s = s2 * 2;
      const int g = ch * 32 + s;
      #pragma unroll
      for (int nt = 0; nt < 4; ++nt)
        cwB[nt] = *(const f16x8*)(wbase + (size_t)(g + 1) * 32768 + nt * 1024);
      {
        const int zg = ((s * 4 + q) ^ sw) << 4;
        f16x8 zf0 = *(const f16x8*)(azb + 0 * 16384 + zg);
        f16x8 zf1 = *(const f16x8*)(azb + 1 * 16384 + zg);
        f16x8 zf2 = *(const f16x8*)(azb + 2 * 16384 + zg);
        f16x8 zf3 = *(const f16x8*)(azb + 3 * 16384 + zg);
        __builtin_amdgcn_s_setprio(1);
        #pragma unroll
        for (int nt = 0; nt < 4; ++nt) {
          acc1[0][nt] = MFMA(cwA[nt], zf0, acc1[0][nt]);
          acc1[1][nt] = MFMA(cwA[nt], zf1, acc1[1][nt]);
          acc1[2][nt] = MFMA(cwA[nt], zf2, acc1[2][nt]);
          acc1[3][nt] = MFMA(cwA[nt], zf3, acc1[3][nt]);
        }
        __builtin_amdgcn_s_setprio(0);
      }
      {
        const int gn = (g + 2 > 63) ? 63 : (g + 2);
        #pragma unroll
        for (int nt = 0; nt < 4; ++nt)
          cwA[nt] = *(const f16x8*)(wbase + (size_t)gn * 32768 + nt * 1024);
      }
      {
        const int zg = (((s + 1) * 4 + q) ^ sw) << 4;
        f16x8 zf0 = *(const f16x8*)(azb + 0 * 16384 + zg);
        f16x8 zf1 = *(const f16x8*)(azb + 1 * 16384 + zg);
        f16x8 zf2 = *(const f16x8*)(azb + 2 * 16384 + zg);
        f16x8 zf3 = *(const f16x8*)(azb + 3 * 16384 + zg);
        __builtin_amdgcn_s_setprio(1);
        #pragma unroll
        for (int nt = 0; nt < 4; ++nt) {
          acc1[0][nt] = MFMA(cwB[nt], zf0, acc1[0][nt]);
          acc1[1][nt] = MFMA(cwB[nt], zf1, acc1[1][nt]);
          acc1[2][nt] = MFMA(cwB[nt], zf2, acc1[2][nt]);
          acc1[3][nt] = MFMA(cwB[nt], zf3, acc1[3][nt]);
        }
        __builtin_amdgcn_s_setprio(0);
      }
    }

    __syncthreads();   // A: all waves finished reading Hb in previous GEMM2

    // ---- chunk epilogue: bias+relu, trace, borderline list, h -> Hb ----
    #pragma unroll
    for (int nt = 0; nt < 4; ++nt) {
      int colc = w * 64 + nt * 16 + q * 4;          // chunk-local col
      int col = ch * 512 + colc;
      f32x4 b4 = *(const f32x4*)&bias1L[col];
      f32x4 c4 = *(const f32x4*)&cvecL[col];
      #pragma unroll
      for (int mt = 0; mt < 4; ++mt) {
        int row = mt * 16 + m16;
        f16x4 hv;
        #pragma unroll
        for (int r = 0; r < 4; ++r) {
          float hp = acc1[mt][nt][r] * (1.f / 1024.f) + b4[r];
          hv[r] = (_Float16)(hp > 0.f ? hp : 0.f);
          if (hp > 0.f) tr[mt] += c4[r];
          if (__builtin_fabsf(hp) < DELTA) {
            uint32_t i_ = atomicAdd(&lcnt, 1u);     // LDS atomic: cheap
            if (i_ < LCAP)
              llist[i_] = ((uint32_t)(bm * 64 + row) << 10) | (uint32_t)col | (uint32_t)r |
                          (hp > 0.f ? 0x80000000u : 0u);
          }
        }
        int gg = (colc >> 3) ^ (row & 7);
        *(f16x4*)((char*)Hb + row * 1024 + gg * 16 + (q & 1) * 8) = hv;
        acc1[mt][nt] = (f32x4){0.f, 0.f, 0.f, 0.f};
      }
    }

    __syncthreads();   // B: Hb(ch) visible to all waves

    // ---- GEMM2: 16 k32-slices, dz += h_chunk @ W2[:, ch*512..]^T ----
    for (int t2 = 0; t2 < 8; ++t2) {
      const int t = t2 * 2;
      const int g = ch * 32 + 16 + t;
      #pragma unroll
      for (int nt = 0; nt < 4; ++nt)
        cwB[nt] = *(const f16x8*)(wbase + (size_t)(g + 1) * 32768 + nt * 1024);
      {
        const int hg = ((t * 4 + q) ^ sw) << 4;
        f16x8 hf0 = *(const f16x8*)(hbb + 0 * 16384 + hg);
        f16x8 hf1 = *(const f16x8*)(hbb + 1 * 16384 + hg);
        f16x8 hf2 = *(const f16x8*)(hbb + 2 * 16384 + hg);
        f16x8 hf3 = *(const f16x8*)(hbb + 3 * 16384 + hg);
        __builtin_amdgcn_s_setprio(1);
        #pragma unroll
        for (int nt = 0; nt < 4; ++nt) {
          acc2[0][nt] = MFMA(cwA[nt], hf0, acc2[0][nt]);
          acc2[1][nt] = MFMA(cwA[nt], hf1, acc2[1][nt]);
          acc2[2][nt] = MFMA(cwA[nt], hf2, acc2[2][nt]);
          acc2[3][nt] = MFMA(cwA[nt], hf3, acc2[3][nt]);
        }
        __builtin_amdgcn_s_setprio(0);
      }
      {
        const int gn = (g + 2 > 63) ? 63 : (g + 2);
        #pragma unroll
        for (int nt = 0; nt < 4; ++nt)
          cwA[nt] = *(const f16x8*)(wbase + (size_t)gn * 32768 + nt * 1024);
      }
      {
        const int hg = (((t + 1) * 4 + q) ^ sw) << 4;
        f16x8 hf0 = *(const f16x8*)(hbb + 0 * 16384 + hg);
        f16x8 hf1 = *(const f16x8*)(hbb + 1 * 16384 + hg);
        f16x8 hf2 = *(const f16x8*)(hbb + 2 * 16384 + hg);
        f16x8 hf3 = *(const f16x8*)(hbb + 3 * 16384 + hg);
        __builtin_amdgcn_s_setprio(1);
        #pragma unroll
        for (int nt = 0; nt < 4; ++nt) {
          acc2[0][nt] = MFMA(cwB[nt], hf0, acc2[0][nt]);
          acc2[1][nt] = MFMA(cwB[nt], hf1, acc2[1][nt]);
          acc2[2][nt] = MFMA(cwB[nt], hf2, acc2[2][nt]);
          acc2[3][nt] = MFMA(cwB[nt], hf3, acc2[3][nt]);
        }
        __builtin_amdgcn_s_setprio(0);
      }
    }
  }

  // ---- dz store: +bias2, f32x4 (4 consecutive cols per thread) ----
  #pragma unroll
  for (int mt = 0; mt < 4; ++mt) {
    int row = bm * 64 + mt * 16 + m16;
    #pragma unroll
    for (int nt = 0; nt < 4; ++nt) {
      int col = w * 64 + nt * 16 + q * 4;
      f32x4 b2v = *(const f32x4*)(bias2 + col);
      *(f32x4*)(out + (size_t)row * 512 + col) = acc2[mt][nt] + b2v;
    }
  }

  // ---- trace: block-local, deterministic ----
  #pragma unroll
  for (int mt = 0; mt < 4; ++mt) {
    tr[mt] += __shfl_xor(tr[mt], 16);
    tr[mt] += __shfl_xor(tr[mt], 32);
  }
  if (q == 0) {
    #pragma unroll
    for (int mt = 0; mt < 4; ++mt) redbuf[w][mt * 16 + m16] = tr[mt];
  }
  __syncthreads();
  if (tid < 64) {
    float s = 0.f;
    #pragma unroll
    for (int ww = 0; ww < 8; ++ww) s += redbuf[ww][tid];
    dlogp[bm * 64 + tid] = -s;
  }

  // ---- flush borderline list: one device atomic per block ----
  if (tid == 0) {
    uint32_t n = lcnt < LCAP ? lcnt : LCAP;
    lbase = atomicAdd(counter, n);
  }
  __syncthreads();
  uint32_t n = lcnt < LCAP ? lcnt : LCAP;
  uint32_t base = lbase;
  for (uint32_t i = tid; i < n; i += 512) {
    uint32_t gi = base + i;
    if (gi < LIST_CAP) list[gi] = llist[i];
  }
}

// ---------------- fixup: recompute borderline h_pre in fp32, patch dlogp ----------------
__global__ __launch_bounds__(256)
void fixup_kernel(const float* __restrict__ z, const float* __restrict__ W1,
                  const float* __restrict__ bias1, const float* __restrict__ cvec,
                  const uint32_t* __restrict__ list, const uint32_t* __restrict__ counter,
                  float* __restrict__ dlogp) {
  uint32_t cnt = *counter;
  if (cnt > LIST_CAP) cnt = LIST_CAP;
  const int wid = (blockIdx.x * 256 + threadIdx.x) >> 6;
  const int lane = threadIdx.x & 63;
  const int nw = gridDim.x * 4;
  for (uint32_t i = wid; i < cnt; i += nw) {
    uint32_t e = list[i];
    int row = (int)((e >> 10) & 16383u);
    int col = (int)(e & 1023u);
    int oldm = (int)(e >> 31);
    float s = 0.f;
    #pragma unroll
    for (int it = 0; it < 8; ++it) {
      int k = it * 64 + lane;
      s += z[(size_t)row * 512 + k] * W1[(size_t)col * 513 + k];
    }
    #pragma unroll
    for (int off = 32; off > 0; off >>= 1) s += __shfl_xor(s, off);
    if (lane == 0) {
      float hp = s + bias1[col];
      int newm = hp > 0.f ? 1 : 0;
      if (newm != oldm)
        atomicAdd(&dlogp[row], oldm ? cvec[col] : -cvec[col]);
    }
  }
}

// ---------------- launcher ----------------
extern "C" void kernel_launch(void* const* d_in, const int* in_sizes, int n_in,
                              void* d_out, int out_size, void* d_ws, size_t ws_size,
                              hipStream_t stream) {
  const float* t  = (const float*)d_in[0];
  const float* z  = (const float*)d_in[1];
  // d_in[2] = logp_z, unused
  const float* W1 = (const float*)d_in[3];
  const float* b1 = (const float*)d_in[4];
  const float* W2 = (const float*)d_in[5];
  const float* b2 = (const float*)d_in[6];

  float* out   = (float*)d_out;
  float* dlogp = out + (size_t)B_ * D_;

  char* ws = (char*)d_ws;
  _Float16* wp    = (_Float16*)ws; ws += (size_t)64 * 32768;     // 2 MB permuted weights
  float*    bias1 = (float*)ws;    ws += 1024 * 4;
  float*    bias2 = (float*)ws;    ws += 512 * 4;
  float*    cvec  = (float*)ws;    ws += 1024 * 4;
  uint32_t* counter = (uint32_t*)ws; ws += 256;
  uint32_t* list  = (uint32_t*)ws; ws += (size_t)LIST_CAP * 4;   // 8 MB

  prep_w<<<772, 256, 0, stream>>>(t, W1, b1, W2, b2, wp, bias1, bias2, cvec, counter);
  fused_kernel<<<256, 512, 0, stream>>>(z, wp, bias1, bias2, cvec, out, dlogp, list, counter);
  fixup_kernel<<<2048, 256, 0, stream>>>(z, W1, bias1, cvec, list, counter, dlogp);
}

// Round 6
// 152.123 us; speedup vs baseline: 1.3354x; 1.0483x over previous
//
#include <hip/hip_runtime.h>
#include <stdint.h>

#define B_   16384
#define D_   512
#define N1_  1024   // 2D
#define K1_  512    // D
#define N2_  512
#define K2_  1024

#define DELTA     4e-3f
#define LCAP      1024u        // per-block LDS list (expected ~209 hits/block)

typedef _Float16 f16x8 __attribute__((ext_vector_type(8)));
typedef _Float16 f16x4 __attribute__((ext_vector_type(4)));
typedef float    f32x4 __attribute__((ext_vector_type(4)));

#define MFMA(a, b, c) __builtin_amdgcn_mfma_f32_16x16x32_f16(a, b, c, 0, 0, 0)

// ---------------- prep: frag-major permuted weights + biases + cvec ----------------
// wp: 64 slices x 32 KB. Slice g (ch=g>>5, ph=g&31) holds the k32-slice of the
// chunk-ch GEMM (ph<16: W1 cols ch*512.., k=ph*32; ph>=16: W2 all 512 dz-cols,
// k=ch*512+(ph-16)*32). Within a slice: [wave w: 4KB][nt 0..3: 1KB][lane: 16B]
// = exactly the A-operand fragment each lane consumes -> 16B/lane coalesced
// global loads, no LDS for weights at all (each weight byte is read by ONE wave).
__global__ __launch_bounds__(256) void prep_w(
    const float* __restrict__ t,
    const float* __restrict__ W1, const float* __restrict__ b1,
    const float* __restrict__ W2, const float* __restrict__ b2,
    _Float16* __restrict__ wp,
    float* __restrict__ bias1, float* __restrict__ bias2,
    float* __restrict__ cvec) {
  int blk = blockIdx.x, tid = threadIdx.x;
  if (blk < 512) {                                  // 131072 granules of 16 B
    int idx = blk * 256 + tid;
    int g = idx >> 11, rem = idx & 2047;
    int w = rem >> 8, nt = (rem >> 6) & 3, lane = rem & 63;
    int m16 = lane & 15, q = lane >> 4;
    int ch = g >> 5, ph = g & 31;
    const float* src;
    float scale;
    if (ph < 16) {                                  // W1 frag: m=h-col, k
      int col = ch * 512 + w * 64 + nt * 16 + m16;
      int k = ph * 32 + q * 8;
      src = W1 + (size_t)col * 513 + k;
      scale = 64.f;
    } else {                                        // W2 frag: m=dz-col, k=h-col
      int col = w * 64 + nt * 16 + m16;
      int k = ch * 512 + (ph - 16) * 32 + q * 8;
      src = W2 + (size_t)col * 1025 + k;
      scale = 1.f;
    }
    f16x8 hv;
    #pragma unroll
    for (int e = 0; e < 8; ++e) hv[e] = (_Float16)(src[e] * scale);
    *(f16x8*)(wp + (size_t)idx * 8) = hv;
  } else if (blk < 516) {                           // biases
    int j = (blk - 512) * 256 + tid;                // [0, 1024)
    float t0 = t[0];
    bias1[j] = b1[j] + t0 * W1[(size_t)j * 513 + 512];
    if (j < 512) bias2[j] = b2[j] + t0 * W2[(size_t)j * 1025 + 1024];
  } else {                                          // c[j] = sum_k W2[k,j]*W1[j,k]
    int wave = tid >> 6, lane = tid & 63;
    int j = (blk - 516) * 4 + wave;                 // [0, 1024)
    float s = 0.f;
    #pragma unroll
    for (int kk = 0; kk < 8; ++kk) {
      int k = lane + kk * 64;
      s += W2[(size_t)k * 1025 + j] * W1[(size_t)j * 513 + k];
    }
    #pragma unroll
    for (int off = 32; off > 0; off >>= 1) s += __shfl_xor(s, off);
    if (lane == 0) cvec[j] = s;
  }
}

// ---------------- fused: GEMM1 + trace + GEMM2 + in-block f32 fixup ----------------
// Block = 64 z-rows, 512 threads (8 waves), grid 256 (1 block/CU).
// Wave w owns cols [w*64,+64) of each 512-col chunk (GEMM1) and of dz (GEMM2).
// Weights: register-double-buffered global->reg stream (compiler-managed waits).
// LDS: Az (64KB swizzled z), Hb (64KB swizzled h chunk). 4 barriers in main loop.
// Borderline ReLU entries stay in LDS (block-local rows!): the tail re-verifies
// them in f32 and corrects dlogp locally -> no 3rd kernel, no global atomics.

__global__ __launch_bounds__(512) void fused_kernel(
    const float* __restrict__ z, const _Float16* __restrict__ wp,
    const float* __restrict__ W1f,
    const float* __restrict__ bias1, const float* __restrict__ bias2,
    const float* __restrict__ cvec,
    float* __restrict__ out, float* __restrict__ dlogp) {
  __shared__ __align__(16) _Float16 Az[64 * 512];   // 64 KB swizzled z (f16 x16)
  __shared__ __align__(16) _Float16 Hb[64 * 512];   // 64 KB swizzled h chunk
  __shared__ __align__(16) float bias1L[1024];      // 4 KB
  __shared__ __align__(16) float cvecL[1024];       // 4 KB
  __shared__ uint32_t llist[LCAP];                  // 4 KB
  __shared__ float redbuf[8][64];                   // 2 KB
  __shared__ float fixv[64];                        // 256 B
  __shared__ uint32_t lcnt;                         // ~142.5 KB total

  const int tid  = threadIdx.x;
  const int lane = tid & 63, w = tid >> 6;          // wave 0..7
  const int q    = lane >> 4, m16 = lane & 15;
  const int sw   = m16 & 7;
  const int bm   = blockIdx.x;

  if (tid == 0) lcnt = 0;
  if (tid < 64) fixv[tid] = 0.f;

  // ---- stage z (f32 -> f16 x16) into swizzled Az ----
  {
    const float* zp = z + (size_t)bm * 64 * 512;
    #pragma unroll
    for (int i = 0; i < 16; ++i) {
      int slot = i * 512 + tid;
      int row = slot >> 7, u8 = slot & 127;
      f32x4 v = *(const f32x4*)(zp + (size_t)row * 512 + u8 * 4);
      f16x4 hv;
      #pragma unroll
      for (int r = 0; r < 4; ++r) hv[r] = (_Float16)(v[r] * 16.f);
      int gz = (u8 >> 1) ^ (row & 7);
      *(f16x4*)((char*)Az + row * 1024 + gz * 16 + (u8 & 1) * 8) = hv;
    }
  }
  for (int i = tid; i < 1024; i += 512) {
    bias1L[i] = bias1[i];
    cvecL[i]  = cvec[i];
  }
  __syncthreads();

  f32x4 acc1[4][4] = {};                            // GEMM1: [mt(row)][nt(col)]
  f32x4 acc2[4][4] = {};                            // GEMM2 accumulates across chunks
  float tr[4] = {0.f, 0.f, 0.f, 0.f};

  const char* azb   = (const char*)Az + m16 * 1024;
  const char* hbb   = (const char*)Hb + m16 * 1024;
  const char* wbase = (const char*)wp + w * 4096 + lane * 16;

  // weight prefetch stream: slice g fragments at wbase + g*32768 + nt*1024
  f16x8 cwA[4], cwB[4];
  #pragma unroll
  for (int nt = 0; nt < 4; ++nt) cwA[nt] = *(const f16x8*)(wbase + nt * 1024);

  for (int ch = 0; ch < 2; ++ch) {
    // ---- GEMM1: 16 k32-slices, h_pre chunk (cols ch*512..+512) ----
    for (int s2 = 0; s2 < 8; ++s2) {
      const int s = s2 * 2;
      const int g = ch * 32 + s;
      #pragma unroll
      for (int nt = 0; nt < 4; ++nt)
        cwB[nt] = *(const f16x8*)(wbase + (size_t)(g + 1) * 32768 + nt * 1024);
      {
        const int zg = ((s * 4 + q) ^ sw) << 4;
        f16x8 zf0 = *(const f16x8*)(azb + 0 * 16384 + zg);
        f16x8 zf1 = *(const f16x8*)(azb + 1 * 16384 + zg);
        f16x8 zf2 = *(const f16x8*)(azb + 2 * 16384 + zg);
        f16x8 zf3 = *(const f16x8*)(azb + 3 * 16384 + zg);
        __builtin_amdgcn_s_setprio(1);
        #pragma unroll
        for (int nt = 0; nt < 4; ++nt) {
          acc1[0][nt] = MFMA(cwA[nt], zf0, acc1[0][nt]);
          acc1[1][nt] = MFMA(cwA[nt], zf1, acc1[1][nt]);
          acc1[2][nt] = MFMA(cwA[nt], zf2, acc1[2][nt]);
          acc1[3][nt] = MFMA(cwA[nt], zf3, acc1[3][nt]);
        }
        __builtin_amdgcn_s_setprio(0);
      }
      {
        const int gn = (g + 2 > 63) ? 63 : (g + 2);
        #pragma unroll
        for (int nt = 0; nt < 4; ++nt)
          cwA[nt] = *(const f16x8*)(wbase + (size_t)gn * 32768 + nt * 1024);
      }
      {
        const int zg = (((s + 1) * 4 + q) ^ sw) << 4;
        f16x8 zf0 = *(const f16x8*)(azb + 0 * 16384 + zg);
        f16x8 zf1 = *(const f16x8*)(azb + 1 * 16384 + zg);
        f16x8 zf2 = *(const f16x8*)(azb + 2 * 16384 + zg);
        f16x8 zf3 = *(const f16x8*)(azb + 3 * 16384 + zg);
        __builtin_amdgcn_s_setprio(1);
        #pragma unroll
        for (int nt = 0; nt < 4; ++nt) {
          acc1[0][nt] = MFMA(cwB[nt], zf0, acc1[0][nt]);
          acc1[1][nt] = MFMA(cwB[nt], zf1, acc1[1][nt]);
          acc1[2][nt] = MFMA(cwB[nt], zf2, acc1[2][nt]);
          acc1[3][nt] = MFMA(cwB[nt], zf3, acc1[3][nt]);
        }
        __builtin_amdgcn_s_setprio(0);
      }
    }

    __syncthreads();   // A: all waves finished reading Hb in previous GEMM2

    // ---- chunk epilogue: bias+relu, trace, borderline list (local row), h -> Hb ----
    #pragma unroll
    for (int nt = 0; nt < 4; ++nt) {
      int colc = w * 64 + nt * 16 + q * 4;          // chunk-local col
      int col = ch * 512 + colc;
      f32x4 b4 = *(const f32x4*)&bias1L[col];
      f32x4 c4 = *(const f32x4*)&cvecL[col];
      #pragma unroll
      for (int mt = 0; mt < 4; ++mt) {
        int row = mt * 16 + m16;
        f16x4 hv;
        #pragma unroll
        for (int r = 0; r < 4; ++r) {
          float hp = acc1[mt][nt][r] * (1.f / 1024.f) + b4[r];
          hv[r] = (_Float16)(hp > 0.f ? hp : 0.f);
          if (hp > 0.f) tr[mt] += c4[r];
          if (__builtin_fabsf(hp) < DELTA) {
            uint32_t i_ = atomicAdd(&lcnt, 1u);     // LDS atomic: cheap
            if (i_ < LCAP)
              llist[i_] = ((uint32_t)row << 10) | (uint32_t)(col + r) |
                          (hp > 0.f ? 0x80000000u : 0u);
          }
        }
        int gg = (colc >> 3) ^ (row & 7);
        *(f16x4*)((char*)Hb + row * 1024 + gg * 16 + (q & 1) * 8) = hv;
        acc1[mt][nt] = (f32x4){0.f, 0.f, 0.f, 0.f};
      }
    }

    __syncthreads();   // B: Hb(ch) visible to all waves

    // ---- GEMM2: 16 k32-slices, dz += h_chunk @ W2[:, ch*512..]^T ----
    for (int t2 = 0; t2 < 8; ++t2) {
      const int t = t2 * 2;
      const int g = ch * 32 + 16 + t;
      #pragma unroll
      for (int nt = 0; nt < 4; ++nt)
        cwB[nt] = *(const f16x8*)(wbase + (size_t)(g + 1) * 32768 + nt * 1024);
      {
        const int hg = ((t * 4 + q) ^ sw) << 4;
        f16x8 hf0 = *(const f16x8*)(hbb + 0 * 16384 + hg);
        f16x8 hf1 = *(const f16x8*)(hbb + 1 * 16384 + hg);
        f16x8 hf2 = *(const f16x8*)(hbb + 2 * 16384 + hg);
        f16x8 hf3 = *(const f16x8*)(hbb + 3 * 16384 + hg);
        __builtin_amdgcn_s_setprio(1);
        #pragma unroll
        for (int nt = 0; nt < 4; ++nt) {
          acc2[0][nt] = MFMA(cwA[nt], hf0, acc2[0][nt]);
          acc2[1][nt] = MFMA(cwA[nt], hf1, acc2[1][nt]);
          acc2[2][nt] = MFMA(cwA[nt], hf2, acc2[2][nt]);
          acc2[3][nt] = MFMA(cwA[nt], hf3, acc2[3][nt]);
        }
        __builtin_amdgcn_s_setprio(0);
      }
      {
        const int gn = (g + 2 > 63) ? 63 : (g + 2);
        #pragma unroll
        for (int nt = 0; nt < 4; ++nt)
          cwA[nt] = *(const f16x8*)(wbase + (size_t)gn * 32768 + nt * 1024);
      }
      {
        const int hg = (((t + 1) * 4 + q) ^ sw) << 4;
        f16x8 hf0 = *(const f16x8*)(hbb + 0 * 16384 + hg);
        f16x8 hf1 = *(const f16x8*)(hbb + 1 * 16384 + hg);
        f16x8 hf2 = *(const f16x8*)(hbb + 2 * 16384 + hg);
        f16x8 hf3 = *(const f16x8*)(hbb + 3 * 16384 + hg);
        __builtin_amdgcn_s_setprio(1);
        #pragma unroll
        for (int nt = 0; nt < 4; ++nt) {
          acc2[0][nt] = MFMA(cwB[nt], hf0, acc2[0][nt]);
          acc2[1][nt] = MFMA(cwB[nt], hf1, acc2[1][nt]);
          acc2[2][nt] = MFMA(cwB[nt], hf2, acc2[2][nt]);
          acc2[3][nt] = MFMA(cwB[nt], hf3, acc2[3][nt]);
        }
        __builtin_amdgcn_s_setprio(0);
      }
    }
  }

  // ---- dz store: +bias2, f32x4 (4 consecutive cols per thread) ----
  #pragma unroll
  for (int mt = 0; mt < 4; ++mt) {
    int row = bm * 64 + mt * 16 + m16;
    #pragma unroll
    for (int nt = 0; nt < 4; ++nt) {
      int col = w * 64 + nt * 16 + q * 4;
      f32x4 b2v = *(const f32x4*)(bias2 + col);
      *(f32x4*)(out + (size_t)row * 512 + col) = acc2[mt][nt] + b2v;
    }
  }

  // ---- trace: block-local partials to LDS ----
  #pragma unroll
  for (int mt = 0; mt < 4; ++mt) {
    tr[mt] += __shfl_xor(tr[mt], 16);
    tr[mt] += __shfl_xor(tr[mt], 32);
  }
  if (q == 0) {
    #pragma unroll
    for (int mt = 0; mt < 4; ++mt) redbuf[w][mt * 16 + m16] = tr[mt];
  }
  __syncthreads();   // redbuf + llist + lcnt final

  // ---- in-block fixup: re-verify borderline h_pre in f32 (entries are OUR rows) ----
  {
    uint32_t n = lcnt < LCAP ? lcnt : LCAP;
    for (uint32_t i = w; i < n; i += 8) {           // one entry per wave
      uint32_t e = llist[i];
      int row  = (int)((e >> 10) & 63u);
      int col  = (int)(e & 1023u);
      int oldm = (int)(e >> 31);
      const float* zr = z   + ((size_t)(bm * 64 + row)) * 512;
      const float* wc = W1f + (size_t)col * 513;
      float s = 0.f;
      #pragma unroll
      for (int it = 0; it < 8; ++it) {
        int k = it * 64 + lane;
        s += zr[k] * wc[k];
      }
      #pragma unroll
      for (int off = 32; off > 0; off >>= 1) s += __shfl_xor(s, off);
      if (lane == 0) {
        float hp = s + bias1L[col];
        int newm = hp > 0.f ? 1 : 0;
        if (newm != oldm)
          atomicAdd(&fixv[row], oldm ? cvecL[col] : -cvecL[col]);
      }
    }
  }
  __syncthreads();

  // ---- final dlogp: -(trace) + corrections, deterministic store ----
  if (tid < 64) {
    float s = 0.f;
    #pragma unroll
    for (int ww = 0; ww < 8; ++ww) s += redbuf[ww][tid];
    dlogp[bm * 64 + tid] = -s + fixv[tid];
  }
}

// ---------------- launcher ----------------
extern "C" void kernel_launch(void* const* d_in, const int* in_sizes, int n_in,
                              void* d_out, int out_size, void* d_ws, size_t ws_size,
                              hipStream_t stream) {
  const float* t  = (const float*)d_in[0];
  const float* z  = (const float*)d_in[1];
  // d_in[2] = logp_z, unused
  const float* W1 = (const float*)d_in[3];
  const float* b1 = (const float*)d_in[4];
  const float* W2 = (const float*)d_in[5];
  const float* b2 = (const float*)d_in[6];

  float* out   = (float*)d_out;
  float* dlogp = out + (size_t)B_ * D_;

  char* ws = (char*)d_ws;
  _Float16* wp    = (_Float16*)ws; ws += (size_t)64 * 32768;     // 2 MB permuted weights
  float*    bias1 = (float*)ws;    ws += 1024 * 4;
  float*    bias2 = (float*)ws;    ws += 512 * 4;
  float*    cvec  = (float*)ws;    ws += 1024 * 4;

  prep_w<<<772, 256, 0, stream>>>(t, W1, b1, W2, b2, wp, bias1, bias2, cvec);
  fused_kernel<<<256, 512, 0, stream>>>(z, wp, W1, bias1, bias2, cvec, out, dlogp);
}